// Round 10
// baseline (278.644 us; speedup 1.0000x reference)
//
#include <hip/hip_runtime.h>
#include <hip/hip_bf16.h>
#include <math.h>

#define N_NODES 50000
#define N_EDGES 600000
#define FDIM    128
#define HROW    64                    // packed bf16 row: 64 uint32 = 128 bf16
#define NCLS    40
#define SCAN_B  1024
#define PADMAX  1400000               // sum of per-node ceil((deg+1)/16)*16 upper bound

typedef __attribute__((ext_vector_type(4))) float  f32x4;
typedef __attribute__((ext_vector_type(8))) __bf16 bf16x8;
union FragU { uint32_t u[4]; bf16x8 v; };

// ---------------- bf16 pack/unpack (RNE) ----------------
__device__ inline float bf16_lo(uint32_t u) { return __uint_as_float(u << 16); }
__device__ inline float bf16_hi(uint32_t u) { return __uint_as_float(u & 0xffff0000u); }
__device__ inline uint32_t bf16_pack(float a, float b) {
    uint32_t ua = __float_as_uint(a), ub = __float_as_uint(b);
    uint32_t ra = (ua + 0x7fffu + ((ua >> 16) & 1u)) >> 16;
    uint32_t rb = (ub + 0x7fffu + ((ub >> 16) & 1u)) >> 16;
    return ra | (rb << 16);
}

// ---------------- block-level weight precompute (shared K5/K6) ----------------
// All 512 threads compute every edge weight of the block's 16 nodes in one flat
// parallel pass -> LDS. Removes the per-node serial adj->ssrc->exp->LDS chain
// from the agg loop. rowL[17] = padded CSR offsets; pads (local >= rdeg) get w=0.
// No max pass (softmax shift-invariant; |e| <= ~10 so exp is f32-safe).
__device__ __forceinline__ void block_weights(
        const int* __restrict__ adj, const float* __restrict__ ssrc,
        const int* rowL, const int* rdegL, const float* sdL,
        float* wlds, int tid) {
    int beg0 = rowL[0], range = rowL[16] - beg0;   // <= 1024 (deg capped ~35)
    for (int i = tid; i < range; i += 512) {
        int gi = beg0 + i;
        int nn = 0;                                 // binary search over 17 offsets
        if (gi >= rowL[nn + 8]) nn += 8;
        if (gi >= rowL[nn + 4]) nn += 4;
        if (gi >= rowL[nn + 2]) nn += 2;
        if (gi >= rowL[nn + 1]) nn += 1;
        float w = 0.f;
        if (gi - rowL[nn] < rdegL[nn]) {
            float e = ssrc[adj[gi]] + sdL[nn];
            e = (e >= 0.f) ? e : 0.2f * e;
            w = __expf(e);
        }
        wlds[i] = w;
    }
}

// ---------------- per-wave aggregation (padded CSR, no syncs) ----------------
// 16 lanes/row x uint4: every round is 16 edges = 4 gathers/lane, all in flight.
// w4 from LDS (broadcast), s4 coalesced int4; pad slots gather row 0 x 0.
__device__ __forceinline__ void wave_agg(
        const uint4* __restrict__ h4, const int* __restrict__ adj,
        const float* wlds, int beg0, int beg, int pdeg,
        int sub, int l16, float acc[8], float& dsum) {
    int rounds = pdeg >> 4;
    for (int t = 0; t < rounds; t++) {
        int j = beg + t * 16 + 4 * sub;
        float4 w4 = *(const float4*)&wlds[j - beg0];
        int4   s4 = *(const int4*)&adj[j];
        uint4 u0 = h4[(size_t)s4.x * 16 + l16];
        uint4 u1 = h4[(size_t)s4.y * 16 + l16];
        uint4 u2 = h4[(size_t)s4.z * 16 + l16];
        uint4 u3 = h4[(size_t)s4.w * 16 + l16];
        dsum += (w4.x + w4.y) + (w4.z + w4.w);
        acc[0] += w4.x * bf16_lo(u0.x) + w4.y * bf16_lo(u1.x) + w4.z * bf16_lo(u2.x) + w4.w * bf16_lo(u3.x);
        acc[1] += w4.x * bf16_hi(u0.x) + w4.y * bf16_hi(u1.x) + w4.z * bf16_hi(u2.x) + w4.w * bf16_hi(u3.x);
        acc[2] += w4.x * bf16_lo(u0.y) + w4.y * bf16_lo(u1.y) + w4.z * bf16_lo(u2.y) + w4.w * bf16_lo(u3.y);
        acc[3] += w4.x * bf16_hi(u0.y) + w4.y * bf16_hi(u1.y) + w4.z * bf16_hi(u2.y) + w4.w * bf16_hi(u3.y);
        acc[4] += w4.x * bf16_lo(u0.z) + w4.y * bf16_lo(u1.z) + w4.z * bf16_lo(u2.z) + w4.w * bf16_lo(u3.z);
        acc[5] += w4.x * bf16_hi(u0.z) + w4.y * bf16_hi(u1.z) + w4.z * bf16_hi(u2.z) + w4.w * bf16_hi(u3.z);
        acc[6] += w4.x * bf16_lo(u0.w) + w4.y * bf16_lo(u1.w) + w4.z * bf16_lo(u2.w) + w4.w * bf16_lo(u3.w);
        acc[7] += w4.x * bf16_hi(u0.w) + w4.y * bf16_hi(u1.w) + w4.z * bf16_hi(u2.w) + w4.w * bf16_hi(u3.w);
    }
    // combine the 4 sub-group partials (each subgroup's 16 lanes are identical in dsum)
    #pragma unroll
    for (int k = 0; k < 8; k++) {
        acc[k] += __shfl_xor(acc[k], 16, 64);
        acc[k] += __shfl_xor(acc[k], 32, 64);
    }
    dsum += __shfl_xor(dsum, 16, 64);
    dsum += __shfl_xor(dsum, 32, 64);
}

// ================= K1: pack_x ∥ W-frag prepack ∥ hist ∥ adj-zero =================
#define PACK_BLOCKS  12500                          // 3.2M dwords / 256
#define WFRAG_BLOCKS 16
#define HIST_BLOCKS  ((N_EDGES / 4 + 255) / 256)    // 586
#define ADJZ_ITEMS   (PADMAX / 4)                   // int4 stores
#define ADJZ_BLOCKS  ((ADJZ_ITEMS + 255) / 256)     // 1368
__global__ __launch_bounds__(256) void k1_setup_hist(
        const float* __restrict__ x, uint32_t* __restrict__ Xp,
        const float* __restrict__ W1, const float* __restrict__ W2,
        uint32_t* __restrict__ wf1, uint32_t* __restrict__ wf2,
        const int* __restrict__ ei, int* __restrict__ counts,
        int* __restrict__ adj) {
    int b = blockIdx.x;
    if (b < PACK_BLOCKS) {
        int i = b * 256 + threadIdx.x;
        float2 v = ((const float2*)x)[i];
        Xp[i] = bf16_pack(v.x, v.y);
        return;
    }
    if (b < PACK_BLOCKS + WFRAG_BLOCKS) {
        // lane holds W[k][n]: n = nt*16 + (lane&15), k = kt*32 + 4g + {e&3} + 16*(e>>2)
        int t = (b - PACK_BLOCKS) * 256 + threadIdx.x;    // 0..4095
        if (t >= 4096) return;
        const float* W = (t < 2048) ? W1 : W2;
        uint32_t*   wf = (t < 2048) ? wf1 : wf2;
        int q = t & 2047;
        int lane = q & 63, nt = (q >> 6) & 7, kt = q >> 9;
        int n = nt * 16 + (lane & 15), g = lane >> 4;
        uint32_t frag[4];
        #pragma unroll
        for (int d = 0; d < 4; d++) {
            int kb = kt * 32 + 4 * g + (d & 1) * 2 + (d >> 1) * 16;
            frag[d] = bf16_pack(W[kb * FDIM + n], W[(kb + 1) * FDIM + n]);
        }
        ((uint4*)wf)[(kt * 8 + nt) * 64 + lane] = *(uint4*)frag;
        return;
    }
    if (b < PACK_BLOCKS + WFRAG_BLOCKS + HIST_BLOCKS) {
        int i = (b - PACK_BLOCKS - WFRAG_BLOCKS) * 256 + threadIdx.x;
        if (i >= N_EDGES / 4) return;
        int4 d = ((const int4*)(ei + N_EDGES))[i];
        atomicAdd(&counts[d.x], 1);
        atomicAdd(&counts[d.y], 1);
        atomicAdd(&counts[d.z], 1);
        atomicAdd(&counts[d.w], 1);
        return;
    }
    int i = (b - PACK_BLOCKS - WFRAG_BLOCKS - HIST_BLOCKS) * 256 + threadIdx.x;
    if (i < ADJZ_ITEMS) ((int4*)adj)[i] = make_int4(0, 0, 0, 0);  // pad slots -> node 0
}

// ================= K2/K3: scan over PADDED degrees =================
// pdeg = ceil((counts+1)/16)*16; self loop folded in; counts memset to 0.
__global__ void scan1_kernel(const int* __restrict__ counts, int* __restrict__ excl,
                             int* __restrict__ bsums, int n) {
    __shared__ int ws[16];
    int gid = blockIdx.x * SCAN_B + threadIdx.x;
    int wv = threadIdx.x >> 6, lane = threadIdx.x & 63;
    int v = (gid < n) ? ((counts[gid] + 16) & ~15) : 0;
    int incl = v;
    #pragma unroll
    for (int off = 1; off < 64; off <<= 1) {
        int t = __shfl_up(incl, off, 64);
        if (lane >= off) incl += t;
    }
    if (lane == 63) ws[wv] = incl;
    __syncthreads();
    int woff = 0;
    for (int i = 0; i < wv; i++) woff += ws[i];
    if (gid < n) excl[gid] = woff + incl - v;
    if (threadIdx.x == SCAN_B - 1) bsums[blockIdx.x] = woff + incl;
}

__global__ void scan3_kernel(int* __restrict__ rowptr, const int* __restrict__ bsums,
                             int* __restrict__ cursor, const int* __restrict__ counts,
                             int n) {
    __shared__ int base_s;
    if (threadIdx.x < 64) {
        int v = (threadIdx.x < (int)blockIdx.x) ? bsums[threadIdx.x] : 0;
        #pragma unroll
        for (int off = 32; off > 0; off >>= 1) v += __shfl_down(v, off, 64);
        if (threadIdx.x == 0) base_s = v;
    }
    __syncthreads();
    int base = base_s;
    int gid = blockIdx.x * SCAN_B + threadIdx.x;
    if (gid < n) {
        int v = rowptr[gid] + base;
        rowptr[gid] = v;
        cursor[gid] = v;
        if (gid == n - 1) rowptr[n] = v + ((counts[gid] + 16) & ~15);
    }
}

// ================= K4: scatter ∥ mfma_gemm1(+scores1) ∥ edge copy =================
#define SCAT_T      ((N_EDGES / 4) + N_NODES)       // 200000
#define SCAT_BLOCKS ((SCAT_T + 255) / 256)          // 782
#define GEMM_BLOCKS ((N_NODES + 63) / 64)           // 782
#define EDGE_ITEMS  ((2 * N_EDGES) / 4)             // 300000 int4
#define EDGE_BLOCKS ((EDGE_ITEMS + 255) / 256)      // 1172
__global__ __launch_bounds__(256) void k4_scatter_gemm_edge(
        const int* __restrict__ ei, int* __restrict__ cursor, int* __restrict__ adj,
        const uint32_t* __restrict__ Xp, const uint32_t* __restrict__ wf,
        const float* __restrict__ a_s, const float* __restrict__ a_d,
        uint32_t* __restrict__ H, float* __restrict__ ssrc, float* __restrict__ sdst,
        float* __restrict__ eout) {
    int b = blockIdx.x;
    if (b < SCAT_BLOCKS) {
        int i = b * 256 + threadIdx.x;
        if (i >= SCAT_T) return;
        if (i < N_EDGES / 4) {
            int4 s4 = ((const int4*)ei)[i];
            int4 d4 = ((const int4*)(ei + N_EDGES))[i];
            adj[atomicAdd(&cursor[d4.x], 1)] = s4.x;
            adj[atomicAdd(&cursor[d4.y], 1)] = s4.y;
            adj[atomicAdd(&cursor[d4.z], 1)] = s4.z;
            adj[atomicAdd(&cursor[d4.w], 1)] = s4.w;
        } else {
            int nd = i - N_EDGES / 4;
            adj[atomicAdd(&cursor[nd], 1)] = nd;
        }
        return;
    }
    if (b < SCAT_BLOCKS + GEMM_BLOCKS) {
        // 4 waves/block, each wave a 16-row x 128-col band; 32 MFMAs/wave.
        int lane = threadIdx.x & 63, wv = threadIdx.x >> 6;
        int row0 = (b - SCAT_BLOCKS) * 64 + wv * 16;
        if (row0 >= N_NODES) return;
        int r = lane & 15, g = lane >> 4;

        const uint32_t* xrow = Xp + (size_t)(row0 + r) * HROW + 2 * g;
        FragU af[4];
        #pragma unroll
        for (int kt = 0; kt < 4; kt++) {
            uint2 lo = *(const uint2*)(xrow + kt * 16);
            uint2 hi = *(const uint2*)(xrow + kt * 16 + 8);
            af[kt].u[0] = lo.x; af[kt].u[1] = lo.y;
            af[kt].u[2] = hi.x; af[kt].u[3] = hi.y;
        }
        f32x4 acc[8] = {};
        #pragma unroll
        for (int kt = 0; kt < 4; kt++) {
            #pragma unroll
            for (int nt = 0; nt < 8; nt++) {
                FragU bfr;
                *(uint4*)bfr.u = ((const uint4*)wf)[(kt * 8 + nt) * 64 + lane];
                acc[nt] = __builtin_amdgcn_mfma_f32_16x16x32_bf16(af[kt].v, bfr.v, acc[nt], 0, 0, 0);
            }
        }
        // fused scores: D layout lane holds D[4g+j][16*nt+r]
        float av_s[8], av_d[8];
        #pragma unroll
        for (int nt = 0; nt < 8; nt++) { av_s[nt] = a_s[16 * nt + r]; av_d[nt] = a_d[16 * nt + r]; }
        #pragma unroll
        for (int j = 0; j < 4; j++) {
            float ps = 0.f, pd = 0.f;
            #pragma unroll
            for (int nt = 0; nt < 8; nt++) { ps += acc[nt][j] * av_s[nt]; pd += acc[nt][j] * av_d[nt]; }
            #pragma unroll
            for (int off = 1; off < 16; off <<= 1) {
                ps += __shfl_xor(ps, off, 64);
                pd += __shfl_xor(pd, off, 64);
            }
            if (r == 0) { ssrc[row0 + 4 * g + j] = ps; sdst[row0 + 4 * g + j] = pd; }
        }
        // pack to bf16: col pairs via shfl_xor(1)
        #pragma unroll
        for (int nt = 0; nt < 8; nt++) {
            #pragma unroll
            for (int j = 0; j < 4; j++) {
                float v0 = acc[nt][j];
                float v1 = __shfl_xor(v0, 1, 64);
                if (!(r & 1))
                    H[(size_t)(row0 + 4 * g + j) * HROW + nt * 8 + (r >> 1)] = bf16_pack(v0, v1);
            }
        }
        return;
    }
    int i = (b - SCAT_BLOCKS - GEMM_BLOCKS) * 256 + threadIdx.x;
    if (i < EDGE_ITEMS) {
        int4 v = ((const int4*)ei)[i];
        ((float4*)eout)[i] = make_float4((float)v.x, (float)v.y, (float)v.z, (float)v.w);
    }
}

// ================= K5: agg1 + gemm2 + scores2 (fused, 8 waves) =================
__global__ __launch_bounds__(512) void k5_agg_gemm(
        const uint32_t* __restrict__ h, const float* __restrict__ ssrc,
        const float* __restrict__ sdst, const int* __restrict__ rowptr,
        const int* __restrict__ counts, const int* __restrict__ adj,
        const float* __restrict__ bias, const uint32_t* __restrict__ wf,
        const float* __restrict__ a_s, const float* __restrict__ a_d,
        uint32_t* __restrict__ Hout, float* __restrict__ ssrc2,
        float* __restrict__ sdst2) {
    int tid = threadIdx.x;
    int wv = tid >> 6, lane = tid & 63;
    int sub = lane >> 4, l16 = lane & 15;
    int row0 = blockIdx.x * 16;
    __shared__ int   rowL[17];
    __shared__ int   rdegL[16];
    __shared__ float sdL[16];
    __shared__ __align__(16) float wlds[1024];
    __shared__ __align__(16) uint32_t rowbuf[16][68];   // 64 data + 4 pad dwords
    __shared__ float scS[8][16], scD[8][16];
    const uint4* h4 = (const uint4*)h;

    if (tid < 17) rowL[tid] = rowptr[row0 + tid];
    if (tid < 16) { rdegL[tid] = counts[row0 + tid] + 1; sdL[tid] = sdst[row0 + tid]; }
    __syncthreads();
    block_weights(adj, ssrc, rowL, rdegL, sdL, wlds, tid);
    __syncthreads();

    int beg0 = rowL[0];
    #pragma unroll
    for (int i = 0; i < 2; i++) {
        int row = wv * 2 + i;
        float acc[8] = {};
        float dsum = 0.f;
        wave_agg(h4, adj, wlds, beg0, rowL[row], rowL[row + 1] - rowL[row],
                 sub, l16, acc, dsum);
        if (sub == 0) {
            float inv = 1.f / dsum;
            float4 b0 = *(const float4*)&bias[l16 * 8];
            float4 b1 = *(const float4*)&bias[l16 * 8 + 4];
            float v0 = fmaxf(acc[0] * inv + b0.x, 0.f), v1 = fmaxf(acc[1] * inv + b0.y, 0.f);
            float v2 = fmaxf(acc[2] * inv + b0.z, 0.f), v3 = fmaxf(acc[3] * inv + b0.w, 0.f);
            float v4 = fmaxf(acc[4] * inv + b1.x, 0.f), v5 = fmaxf(acc[5] * inv + b1.y, 0.f);
            float v6 = fmaxf(acc[6] * inv + b1.z, 0.f), v7 = fmaxf(acc[7] * inv + b1.w, 0.f);
            uint4 o;
            o.x = bf16_pack(v0, v1); o.y = bf16_pack(v2, v3);
            o.z = bf16_pack(v4, v5); o.w = bf16_pack(v6, v7);
            *(uint4*)&rowbuf[row][l16 * 4] = o;
        }
    }
    __syncthreads();

    // ---- phase 2: 16x128 GEMM tile, wave wv owns nt = wv ----
    int r = lane & 15, g = lane >> 4;
    FragU af[4];
    #pragma unroll
    for (int kt = 0; kt < 4; kt++) {
        uint2 lo = *(const uint2*)&rowbuf[r][kt * 16 + 2 * g];
        uint2 hi = *(const uint2*)&rowbuf[r][kt * 16 + 2 * g + 8];
        af[kt].u[0] = lo.x; af[kt].u[1] = lo.y;
        af[kt].u[2] = hi.x; af[kt].u[3] = hi.y;
    }
    f32x4 acc2 = {};
    #pragma unroll
    for (int kt = 0; kt < 4; kt++) {
        FragU bfr;
        *(uint4*)bfr.u = ((const uint4*)wf)[(kt * 8 + wv) * 64 + lane];
        acc2 = __builtin_amdgcn_mfma_f32_16x16x32_bf16(af[kt].v, bfr.v, acc2, 0, 0, 0);
    }
    // ---- phase 3: score partials (this wave's 16 cols), cross-wave via LDS ----
    float as0 = a_s[16 * wv + r], ad0 = a_d[16 * wv + r];
    #pragma unroll
    for (int j = 0; j < 4; j++) {
        float ps = acc2[j] * as0;
        float pd = acc2[j] * ad0;
        #pragma unroll
        for (int off = 1; off < 16; off <<= 1) {
            ps += __shfl_xor(ps, off, 64);
            pd += __shfl_xor(pd, off, 64);
        }
        if (r == 0) { scS[wv][4 * g + j] = ps; scD[wv][4 * g + j] = pd; }
    }
    // ---- phase 4: bf16 pack + global H write (cols 16wv..16wv+15) ----
    #pragma unroll
    for (int j = 0; j < 4; j++) {
        float v0 = acc2[j];
        float v1 = __shfl_xor(v0, 1, 64);
        if (!(r & 1))
            Hout[(size_t)(row0 + 4 * g + j) * HROW + wv * 8 + (r >> 1)] = bf16_pack(v0, v1);
    }
    __syncthreads();
    if (tid < 16) {
        float s = 0.f;
        #pragma unroll
        for (int w = 0; w < 8; w++) s += scS[w][tid];
        ssrc2[row0 + tid] = s;
    } else if (tid < 32) {
        int q = tid - 16;
        float s = 0.f;
        #pragma unroll
        for (int w = 0; w < 8; w++) s += scD[w][q];
        sdst2[row0 + q] = s;
    }
}

// ================= K6: agg2 + classifier (fused, 8 waves) =================
__global__ __launch_bounds__(512) void k6_agg_cls(
        const uint32_t* __restrict__ h, const float* __restrict__ ssrc,
        const float* __restrict__ sdst, const int* __restrict__ rowptr,
        const int* __restrict__ counts, const int* __restrict__ adj,
        const float* __restrict__ bias, const float* __restrict__ Wl,
        const float* __restrict__ bl, float* __restrict__ out) {
    int tid = threadIdx.x;
    int wv = tid >> 6, lane = tid & 63;
    int sub = lane >> 4, l16 = lane & 15;
    int row0 = blockIdx.x * 16;
    __shared__ int   rowL[17];
    __shared__ int   rdegL[16];
    __shared__ float sdL[16];
    __shared__ __align__(16) float wlds[1024];
    __shared__ float xs[16][FDIM];
    const uint4* h4 = (const uint4*)h;

    if (tid < 17) rowL[tid] = rowptr[row0 + tid];
    if (tid < 16) { rdegL[tid] = counts[row0 + tid] + 1; sdL[tid] = sdst[row0 + tid]; }
    __syncthreads();
    block_weights(adj, ssrc, rowL, rdegL, sdL, wlds, tid);
    __syncthreads();

    int beg0 = rowL[0];
    #pragma unroll
    for (int i = 0; i < 2; i++) {
        int row = wv * 2 + i;
        float acc[8] = {};
        float dsum = 0.f;
        wave_agg(h4, adj, wlds, beg0, rowL[row], rowL[row + 1] - rowL[row],
                 sub, l16, acc, dsum);
        if (sub == 0) {
            float inv = 1.f / dsum;
            float4 b0 = *(const float4*)&bias[l16 * 8];
            float4 b1 = *(const float4*)&bias[l16 * 8 + 4];
            float4 p0, p1;
            p0.x = acc[0] * inv + b0.x; p0.y = acc[1] * inv + b0.y;
            p0.z = acc[2] * inv + b0.z; p0.w = acc[3] * inv + b0.w;
            p1.x = acc[4] * inv + b1.x; p1.y = acc[5] * inv + b1.y;
            p1.z = acc[6] * inv + b1.z; p1.w = acc[7] * inv + b1.w;
            *(float4*)&xs[row][l16 * 8]     = p0;
            *(float4*)&xs[row][l16 * 8 + 4] = p1;
        }
    }
    __syncthreads();

    // ---- classifier: wave hw handles rows hw*2, hw*2+1 ----
    int c = tid & 63, hw = tid >> 6;
    float acc[2];
    float blc = (c < NCLS) ? bl[c] : 0.f;
    acc[0] = blc; acc[1] = blc;

    #pragma unroll 2
    for (int k = 0; k < FDIM; k += 4) {
        float w0 = 0.f, w1 = 0.f, w2 = 0.f, w3 = 0.f;
        if (c < NCLS) {
            w0 = Wl[(k + 0) * NCLS + c]; w1 = Wl[(k + 1) * NCLS + c];
            w2 = Wl[(k + 2) * NCLS + c]; w3 = Wl[(k + 3) * NCLS + c];
        }
        #pragma unroll
        for (int r = 0; r < 2; r++) {
            float4 xv = *(const float4*)&xs[hw * 2 + r][k];
            acc[r] += xv.x * w0 + xv.y * w1 + xv.z * w2 + xv.w * w3;
        }
    }
    #pragma unroll
    for (int r = 0; r < 2; r++) {
        float v = (c < NCLS) ? acc[r] : -INFINITY;
        float mx = v;
        #pragma unroll
        for (int off = 32; off > 0; off >>= 1) mx = fmaxf(mx, __shfl_xor(mx, off, 64));
        float ex = (c < NCLS) ? expf(v - mx) : 0.f;
        #pragma unroll
        for (int off = 32; off > 0; off >>= 1) ex += __shfl_xor(ex, off, 64);
        float ls = logf(ex);
        if (c < NCLS) out[(size_t)(row0 + hw * 2 + r) * NCLS + c] = v - mx - ls;
    }
}

extern "C" void kernel_launch(void* const* d_in, const int* in_sizes, int n_in,
                              void* d_out, int out_size, void* d_ws, size_t ws_size,
                              hipStream_t stream) {
    const float* x   = (const float*)d_in[0];
    const int*   ei  = (const int*)d_in[1];
    const float* W1  = (const float*)d_in[2];
    const float* a1s = (const float*)d_in[3];
    const float* a1d = (const float*)d_in[4];
    const float* b1  = (const float*)d_in[5];
    const float* W2  = (const float*)d_in[6];
    const float* a2s = (const float*)d_in[7];
    const float* a2d = (const float*)d_in[8];
    const float* b2  = (const float*)d_in[9];
    const float* Wl  = (const float*)d_in[10];
    const float* bl  = (const float*)d_in[11];
    float* out = (float*)d_out;

    char* ws = (char*)d_ws;
    size_t off = 0;
    auto alloc = [&](size_t bytes) {
        void* p = ws + off;
        off = (off + bytes + 255) & ~(size_t)255;
        return p;
    };
    int*      row_ptr = (int*)alloc((N_NODES + 1) * sizeof(int));
    int*      cursor  = (int*)alloc(N_NODES * sizeof(int));
    int*      counts  = (int*)alloc(N_NODES * sizeof(int));
    int*      bsums   = (int*)alloc(64 * sizeof(int));
    int*      adj     = (int*)alloc(PADMAX * sizeof(int));
    uint32_t* Xp      = (uint32_t*)alloc((size_t)N_NODES * HROW * sizeof(uint32_t));
    uint32_t* hA      = (uint32_t*)alloc((size_t)N_NODES * HROW * sizeof(uint32_t));
    uint32_t* hB      = (uint32_t*)alloc((size_t)N_NODES * HROW * sizeof(uint32_t));
    float*    ssrc    = (float*)alloc(N_NODES * sizeof(float));
    float*    sdst    = (float*)alloc(N_NODES * sizeof(float));
    float*    ssrc2   = (float*)alloc(N_NODES * sizeof(float));
    float*    sdst2   = (float*)alloc(N_NODES * sizeof(float));
    uint32_t* wf1     = (uint32_t*)alloc(2048 * 4 * sizeof(uint32_t));
    uint32_t* wf2     = (uint32_t*)alloc(2048 * 4 * sizeof(uint32_t));

    // K0: zero the histogram (self loops folded into scan's +16 rounding)
    hipMemsetAsync(counts, 0, N_NODES * sizeof(int), stream);

    // K1: pack x ∥ prepack W frags ∥ histogram ∥ zero padded adj
    hipLaunchKernelGGL(k1_setup_hist,
                       dim3(PACK_BLOCKS + WFRAG_BLOCKS + HIST_BLOCKS + ADJZ_BLOCKS), dim3(256),
                       0, stream, x, Xp, W1, W2, wf1, wf2, ei, counts, adj);

    // K2/K3: scan of padded degrees
    int nscan = (N_NODES + SCAN_B - 1) / SCAN_B;  // 49
    hipLaunchKernelGGL(scan1_kernel, dim3(nscan), dim3(SCAN_B), 0, stream, counts, row_ptr, bsums, N_NODES);
    hipLaunchKernelGGL(scan3_kernel, dim3(nscan), dim3(SCAN_B), 0, stream, row_ptr, bsums, cursor, counts, N_NODES);

    // K4: scatter ∥ gemm1(+scores1) ∥ edge pass-through
    hipLaunchKernelGGL(k4_scatter_gemm_edge, dim3(SCAT_BLOCKS + GEMM_BLOCKS + EDGE_BLOCKS), dim3(256),
                       0, stream, ei, cursor, adj, Xp, wf1, a1s, a1d, hA, ssrc, sdst,
                       out + (size_t)N_NODES * NCLS);

    // K5: agg1 + gemm2 + scores2
    hipLaunchKernelGGL(k5_agg_gemm, dim3(N_NODES / 16), dim3(512), 0, stream,
                       hA, ssrc, sdst, row_ptr, counts, adj, b1, wf2, a2s, a2d, hB, ssrc2, sdst2);

    // K6: agg2 + classifier
    hipLaunchKernelGGL(k6_agg_cls, dim3(N_NODES / 16), dim3(512), 0, stream,
                       hB, ssrc2, sdst2, row_ptr, counts, adj, b2, Wl, bl, out);
}